// Round 2
// baseline (1338.162 us; speedup 1.0000x reference)
//
#include <hip/hip_runtime.h>
#include <stdint.h>

typedef __attribute__((ext_vector_type(8))) _Float16 half8;
typedef __attribute__((ext_vector_type(2))) _Float16 half2v;
typedef __attribute__((ext_vector_type(4))) float floatx4;
typedef __attribute__((ext_vector_type(4))) uint32_t uint4v;

#define KDIM 4096
#define NDIM 11008
#define BM 128
#define BN 128
#define BK 64
#define NKT (KDIM / BK)

#define GLOAD_LDS16(gsrc, ldst)                                                        \
  __builtin_amdgcn_global_load_lds(                                                    \
      (const __attribute__((address_space(1))) void*)(gsrc),                           \
      (__attribute__((address_space(3))) void*)(ldst), 16, 0, 0)

static __device__ __forceinline__ uint32_t pkrtz(float a, float b) {
  // exact here: all staged values are fp16-representable, RTZ == RTN
  auto h = __builtin_amdgcn_cvt_pkrtz(a, b);
  return __builtin_bit_cast(uint32_t, h);
}

__global__ __launch_bounds__(256, 2)
void l4b_gemm(const float* __restrict__ X,       // fp16 values widened to fp32 by harness
              const int* __restrict__ PW,
              const float* __restrict__ SC,      // fp16 values widened to fp32
              float* __restrict__ OUT)           // harness reads fp32
{
  // A: fp32 LDS tile [128 rows][64 floats] (256B rows = 16 x 16B slots), dbuf.
  //   swizzle: phys_slot = s ^ ((r&7)<<1) ^ ((r>>3)&1)  (pair-XOR + bit0 parity ->
  //   16-lane fragment reads are exactly 2-way bank aliased = free)
  // B: fp16 LDS tile [128 rows][64 halfs] (128B rows = 8 x 16B slots):
  //   phys_slot = s ^ (r&7)
  __shared__ float    laf[2][BM * BK];
  __shared__ _Float16 lb[BN * BK];

  const int tid  = threadIdx.x;
  const int lane = tid & 63;
  const int wave = tid >> 6;

  const int nbx = NDIM / BN;  // 86
  const int bx  = blockIdx.x % nbx;
  const int by  = blockIdx.x / nbx;
  const int64_t brow = (int64_t)by * BM;
  const int     bcol = bx * BN;

  // 2x2 wave grid, each wave owns a 64x64 output sub-tile
  const int wr = (wave >> 1) * 64;
  const int wc = (wave & 1) * 64;

  floatx4 acc[4][4];
#pragma unroll
  for (int i = 0; i < 4; ++i)
#pragma unroll
    for (int j = 0; j < 4; ++j)
      acc[i][j] = (floatx4)(0.0f);

  // ---- B staging assignment: thread -> (n = tid&127, kp0 = tid>>7) ----
  const int sn   = tid & 127;
  const int skp0 = tid >> 7;
  const int*   const pwcol = PW + bcol + sn;
  const float* const sccol = SC + bcol + sn;

  // ---- A staging: per wave 8 gload_lds calls, call i writes rows wave*32+i*4..+3
  //      (4 rows x 256B = 1024B = 64 lanes x 16B, linear dest) ----
  int a_off[8];  // per-lane float offset from X + brow*KDIM + kt*BK
  {
    const int sub = lane >> 4;   // row within 4-row group
    const int p   = lane & 15;   // physical slot written by this lane
#pragma unroll
    for (int i = 0; i < 8; ++i) {
      const int r = wave * 32 + i * 4 + sub;                 // tile row
      const int s = p ^ ((r & 7) << 1) ^ ((r >> 3) & 1);     // logical slot
      a_off[i] = r * KDIM + s * 4;
    }
  }
  const float* const abase = X + brow * (int64_t)KDIM;

  int w[4];
  float sch;
  {  // prologue: prefetch kt=0
    const int* p = pwcol + skp0 * NDIM;
#pragma unroll
    for (int j = 0; j < 4; ++j) w[j] = p[j * 2 * NDIM];
    sch = sccol[0];
#pragma unroll
    for (int i = 0; i < 8; ++i)
      GLOAD_LDS16(abase + a_off[i], &laf[0][(wave * 32 + i * 4) * BK]);
  }

  const int fr = lane & 15;
  const int fq = lane >> 4;

  for (int kt = 0; kt < NKT; ++kt) {
    const int buf = kt & 1;
    __syncthreads();  // drains A gload_lds (vmcnt) + w loads; prev MFMA reads done

    // ---- dequant w -> fp16, swizzled ds_write_b128 into lb ----
    {
      const _Float16 ss = (_Float16)(sch * (1.0f / 7.5f));
      half2v ssv; ssv[0] = ss; ssv[1] = ss;
      half2v off; off[0] = (_Float16)(-1032.0f); off[1] = (_Float16)(-1032.0f);
#pragma unroll
      for (int j = 0; j < 4; ++j) {
        const uint32_t q  = (uint32_t)w[j];
        const uint32_t a0 = (q & 0x000F000Fu) | 0x64006400u;          // {1024+n0,1024+n4}
        const uint32_t a1 = ((q >> 4) & 0x000F000Fu) | 0x64006400u;   // {n1,n5}
        const uint32_t a2 = ((q >> 8) & 0x000F000Fu) | 0x64006400u;   // {n2,n6}
        const uint32_t a3 = ((q >> 12) & 0x000F000Fu) | 0x64006400u;  // {n3,n7}
        const uint32_t p0 = __builtin_amdgcn_perm(a1, a0, 0x05040100u);  // {k0,k1}
        const uint32_t p1 = __builtin_amdgcn_perm(a3, a2, 0x05040100u);  // {k2,k3}
        const uint32_t p2 = __builtin_amdgcn_perm(a1, a0, 0x07060302u);  // {k4,k5}
        const uint32_t p3 = __builtin_amdgcn_perm(a3, a2, 0x07060302u);  // {k6,k7}
        uint4v u;
        u[0] = __builtin_bit_cast(uint32_t, (__builtin_bit_cast(half2v, p0) + off) * ssv);
        u[1] = __builtin_bit_cast(uint32_t, (__builtin_bit_cast(half2v, p1) + off) * ssv);
        u[2] = __builtin_bit_cast(uint32_t, (__builtin_bit_cast(half2v, p2) + off) * ssv);
        u[3] = __builtin_bit_cast(uint32_t, (__builtin_bit_cast(half2v, p3) + off) * ssv);
        const int kp = skp0 + 2 * j;
        *(half8*)&lb[sn * BK + ((kp ^ (sn & 7)) * 8)] = __builtin_bit_cast(half8, u);
      }
    }

    __syncthreads();  // lb + laf[buf] visible

    // ---- issue kt+1 prefetches; they fly through the MFMA phase ----
    if (kt + 1 < NKT) {
      const int* p = pwcol + ((kt + 1) * 8 + skp0) * NDIM;
#pragma unroll
      for (int j = 0; j < 4; ++j) w[j] = p[j * 2 * NDIM];
      sch = sccol[(int64_t)((kt + 1) >> 1) * NDIM];
      const float* asrc = abase + (kt + 1) * BK;
#pragma unroll
      for (int i = 0; i < 8; ++i)
        GLOAD_LDS16(asrc + a_off[i], &laf[buf ^ 1][(wave * 32 + i * 4) * BK]);
    }

    // ---- MFMA phase ----
#pragma unroll
    for (int ks = 0; ks < 2; ++ks) {
      half8 af[4], bf[4];
#pragma unroll
      for (int fm = 0; fm < 4; ++fm) {
        const int m    = wr + fm * 16 + fr;
        const int pair = ((ks * 4 + fq) ^ (m & 7));
        const int b    = (m >> 3) & 1;
        const int base = m * BK + pair * 8;
        floatx4 lo = *(const floatx4*)&laf[buf][base + b * 4];        // logical slot s0
        floatx4 hi = *(const floatx4*)&laf[buf][base + (b ^ 1) * 4];  // logical slot s0+1
        uint4v u;
        u[0] = pkrtz(lo[0], lo[1]);
        u[1] = pkrtz(lo[2], lo[3]);
        u[2] = pkrtz(hi[0], hi[1]);
        u[3] = pkrtz(hi[2], hi[3]);
        af[fm] = __builtin_bit_cast(half8, u);
      }
#pragma unroll
      for (int fn = 0; fn < 4; ++fn) {
        const int n   = wc + fn * 16 + fr;
        const int ksl = ks * 4 + fq;
        bf[fn] = *(const half8*)&lb[n * BK + ((ksl ^ (n & 7)) * 8)];
      }
#pragma unroll
      for (int fm = 0; fm < 4; ++fm)
#pragma unroll
        for (int fn = 0; fn < 4; ++fn)
          acc[fm][fn] =
              __builtin_amdgcn_mfma_f32_16x16x32_f16(af[fm], bf[fn], acc[fm][fn], 0, 0, 0);
    }
  }

  // ---- epilogue: C/D layout col=lane&15, row=(lane>>4)*4+reg; fp32 out ----
#pragma unroll
  for (int fm = 0; fm < 4; ++fm)
#pragma unroll
    for (int fn = 0; fn < 4; ++fn)
#pragma unroll
      for (int r = 0; r < 4; ++r) {
        const int64_t row = brow + wr + fm * 16 + fq * 4 + r;
        const int     col = bcol + wc + fn * 16 + fr;
        OUT[row * NDIM + col] = acc[fm][fn][r];
      }
}

extern "C" void kernel_launch(void* const* d_in, const int* in_sizes, int n_in,
                              void* d_out, int out_size, void* d_ws, size_t ws_size,
                              hipStream_t stream) {
  const float* X   = (const float*)d_in[0];
  const int*   PW  = (const int*)d_in[1];
  const float* SC  = (const float*)d_in[2];
  float*       OUT = (float*)d_out;

  const int M = in_sizes[0] / KDIM;          // 8192
  const int grid = (M / BM) * (NDIM / BN);   // 64 * 86 = 5504
  l4b_gemm<<<grid, 256, 0, stream>>>(X, PW, SC, OUT);
}

// Round 3
// 1168.563 us; speedup vs baseline: 1.1451x; 1.1451x over previous
//
#include <hip/hip_runtime.h>
#include <stdint.h>

typedef __attribute__((ext_vector_type(8))) _Float16 half8;
typedef __attribute__((ext_vector_type(2))) _Float16 half2v;
typedef __attribute__((ext_vector_type(4))) float floatx4;
typedef __attribute__((ext_vector_type(4))) uint32_t uint4v;

#define KDIM 4096
#define NDIM 11008
#define BM 256
#define BN 256
#define BK 64
#define NKT (KDIM / BK)  // 64

static __device__ __forceinline__ uint32_t pkrtz(float a, float b) {
  // exact: staged values are fp16-representable, RTZ == RTN
  auto h = __builtin_amdgcn_cvt_pkrtz(a, b);
  return __builtin_bit_cast(uint32_t, h);
}

__global__ __launch_bounds__(512, 2)
void l4b_gemm(const float* __restrict__ X,   // fp16 widened to fp32 by harness
              const int* __restrict__ PW,
              const float* __restrict__ SC,  // fp16 widened to fp32
              float* __restrict__ OUT)       // fp32 out
{
  // Both tiles fp16, double buffered. Row = 64 halves = 128B = 8 x 16B slots.
  // Swizzle: phys_slot = s ^ (row & 7)  (conflict-free b128 reads/writes)
  __shared__ alignas(16) _Float16 la[2][BM * BK];  // 32KB x2
  __shared__ alignas(16) _Float16 lb[2][BN * BK];  // 32KB x2

  const int tid  = threadIdx.x;
  const int lane = tid & 63;
  const int wave = tid >> 6;

  // XCD-aware bijective swizzle (grid = 1376 = 8*172)
  const int nbx = NDIM / BN;  // 43
  const int cpx = (int)gridDim.x >> 3;
  const int wg  = (blockIdx.x & 7) * cpx + (blockIdx.x >> 3);
  const int by  = wg / nbx;
  const int bx  = wg - by * nbx;
  const int64_t brow = (int64_t)by * BM;
  const int     bcol = bx * BN;

  // 2M x 4N wave grid, wave tile 128x64
  const int wr = (wave >> 2) * 128;
  const int wc = (wave & 3) * 64;
  const int fr = lane & 15;
  const int fq = lane >> 4;

  floatx4 acc[8][4];
#pragma unroll
  for (int i = 0; i < 8; ++i)
#pragma unroll
    for (int j = 0; j < 4; ++j) acc[i][j] = (floatx4)(0.0f);

  // ---- A staging: thread -> (row = tid>>1, half = tid&1), 32 floats ----
  const int ar = tid >> 1;
  const int ah = tid & 1;
  const float* const aptr = X + (brow + ar) * (int64_t)KDIM + ah * 32;

  // ---- B staging: thread -> (col = tid&255, kq = tid>>8), 4 int32 ----
  const int bc  = tid & 255;
  const int bkq = tid >> 8;
  const int*   const pwcol = PW + bcol + bc;
  const float* const sccol = SC + bcol + bc;

  floatx4 ra[8];
  int     rw[4];
  float   rsc;

#define LOAD_TILE(t)                                                       \
  do {                                                                     \
    const float* ap = aptr + (t) * BK;                                     \
    _Pragma("unroll") for (int i = 0; i < 8; ++i)                          \
        ra[i] = *(const floatx4*)(ap + i * 4);                             \
    const int* pp = pwcol + ((t) * 8 + bkq) * NDIM;                        \
    _Pragma("unroll") for (int j = 0; j < 4; ++j)                          \
        rw[j] = pp[j * 2 * NDIM];                                          \
    rsc = sccol[(int64_t)((t) >> 1) * NDIM];                               \
  } while (0)

#define WRITE_TILE(buf)                                                    \
  do {                                                                     \
    _Pragma("unroll") for (int i2 = 0; i2 < 4; ++i2) {                     \
      uint4v u;                                                            \
      u[0] = pkrtz(ra[2 * i2][0], ra[2 * i2][1]);                          \
      u[1] = pkrtz(ra[2 * i2][2], ra[2 * i2][3]);                          \
      u[2] = pkrtz(ra[2 * i2 + 1][0], ra[2 * i2 + 1][1]);                  \
      u[3] = pkrtz(ra[2 * i2 + 1][2], ra[2 * i2 + 1][3]);                  \
      const int s = ah * 4 + i2;                                           \
      *(half8*)&la[buf][ar * BK + ((s ^ (ar & 7)) * 8)] =                  \
          __builtin_bit_cast(half8, u);                                    \
    }                                                                      \
    const _Float16 ss = (_Float16)(rsc * (1.0f / 7.5f));                   \
    half2v ssv; ssv[0] = ss; ssv[1] = ss;                                  \
    half2v off; off[0] = (_Float16)(-1032.0f); off[1] = (_Float16)(-1032.0f); \
    _Pragma("unroll") for (int j = 0; j < 4; ++j) {                        \
      const uint32_t q  = (uint32_t)rw[j];                                 \
      const uint32_t a0 = (q & 0x000F000Fu) | 0x64006400u;                 \
      const uint32_t a1 = ((q >> 4) & 0x000F000Fu) | 0x64006400u;          \
      const uint32_t a2 = ((q >> 8) & 0x000F000Fu) | 0x64006400u;          \
      const uint32_t a3 = ((q >> 12) & 0x000F000Fu) | 0x64006400u;         \
      const uint32_t p0 = __builtin_amdgcn_perm(a1, a0, 0x05040100u);      \
      const uint32_t p1 = __builtin_amdgcn_perm(a3, a2, 0x05040100u);      \
      const uint32_t p2 = __builtin_amdgcn_perm(a1, a0, 0x07060302u);      \
      const uint32_t p3 = __builtin_amdgcn_perm(a3, a2, 0x07060302u);      \
      uint4v u;                                                            \
      u[0] = __builtin_bit_cast(uint32_t, (__builtin_bit_cast(half2v, p0) + off) * ssv); \
      u[1] = __builtin_bit_cast(uint32_t, (__builtin_bit_cast(half2v, p1) + off) * ssv); \
      u[2] = __builtin_bit_cast(uint32_t, (__builtin_bit_cast(half2v, p2) + off) * ssv); \
      u[3] = __builtin_bit_cast(uint32_t, (__builtin_bit_cast(half2v, p3) + off) * ssv); \
      const int kp = bkq + 2 * j;                                          \
      *(half8*)&lb[buf][bc * BK + ((kp ^ (bc & 7)) * 8)] =                 \
          __builtin_bit_cast(half8, u);                                    \
    }                                                                      \
  } while (0)

#define BARRIER()                                                          \
  do {                                                                     \
    __builtin_amdgcn_sched_barrier(0);                                     \
    asm volatile("s_waitcnt lgkmcnt(0)" ::: "memory");                     \
    __builtin_amdgcn_s_barrier();                                          \
    __builtin_amdgcn_sched_barrier(0);                                     \
  } while (0)

  // ---- prologue ----
  LOAD_TILE(0);
  WRITE_TILE(0);   // implicit vmcnt waits inserted by compiler
  LOAD_TILE(1);    // in flight across the barrier
  BARRIER();

  for (int kt = 0; kt < NKT; ++kt) {
    const int buf = kt & 1;

    if (kt + 1 < NKT) WRITE_TILE(buf ^ 1);  // consumes regs of tile kt+1
    if (kt + 2 < NKT) LOAD_TILE(kt + 2);    // issue; flies through MFMA phase

    // ---- MFMA phase on buf ----
    const _Float16* lap = la[buf];
    const _Float16* lbp = lb[buf];
    __builtin_amdgcn_s_setprio(1);
#pragma unroll
    for (int ks = 0; ks < 2; ++ks) {
      const int ksl = ks * 4 + fq;
      half8 bfr[4];
#pragma unroll
      for (int fn = 0; fn < 4; ++fn) {
        const int n = wc + fn * 16 + fr;
        bfr[fn] = *(const half8*)&lbp[n * BK + ((ksl ^ (n & 7)) * 8)];
      }
#pragma unroll
      for (int fm = 0; fm < 8; ++fm) {
        const int m = wr + fm * 16 + fr;
        const half8 af = *(const half8*)&lap[m * BK + ((ksl ^ (m & 7)) * 8)];
#pragma unroll
        for (int fn = 0; fn < 4; ++fn)
          acc[fm][fn] =
              __builtin_amdgcn_mfma_f32_16x16x32_f16(af, bfr[fn], acc[fm][fn], 0, 0, 0);
      }
    }
    __builtin_amdgcn_s_setprio(0);

    BARRIER();
  }

  // ---- epilogue: C/D map col=lane&15, row=(lane>>4)*4+reg ----
#pragma unroll
  for (int fm = 0; fm < 8; ++fm)
#pragma unroll
    for (int fn = 0; fn < 4; ++fn)
#pragma unroll
      for (int r = 0; r < 4; ++r) {
        const int64_t row = brow + wr + fm * 16 + fq * 4 + r;
        const int     col = bcol + wc + fn * 16 + fr;
        OUT[row * NDIM + col] = acc[fm][fn][r];
      }
}

extern "C" void kernel_launch(void* const* d_in, const int* in_sizes, int n_in,
                              void* d_out, int out_size, void* d_ws, size_t ws_size,
                              hipStream_t stream) {
  const float* X   = (const float*)d_in[0];
  const int*   PW  = (const int*)d_in[1];
  const float* SC  = (const float*)d_in[2];
  float*       OUT = (float*)d_out;

  const int M    = in_sizes[0] / KDIM;             // 8192
  const int grid = (M / BM) * (NDIM / BN);         // 32 * 43 = 1376
  l4b_gemm<<<grid, 512, 0, stream>>>(X, PW, SC, OUT);
}